// Round 5
// baseline (294.112 us; speedup 1.0000x reference)
//
#include <hip/hip_runtime.h>
#include <hip/hip_bf16.h>

#define K_DIM 4096
#define N_DIM 4096
#define M_DIM 4096

typedef __attribute__((ext_vector_type(8)))  short bf16x8;    // 8 bf16, 4 VGPRs
typedef __attribute__((ext_vector_type(16))) float f32x16;    // 32x32 MFMA acc
typedef __attribute__((ext_vector_type(8)))  unsigned short u16x8;

// ---------- fp32 -> bf16 (round-to-nearest-even) ----------
__device__ __forceinline__ unsigned short f2bf(float f) {
    union { float f; unsigned int u; } v; v.f = f;
    unsigned int u = v.u;
    return (unsigned short)((u + 0x7fffu + ((u >> 16) & 1u)) >> 16);
}

// ---------- fused convert: x and W in one launch ----------
__global__ void cvt2_f32_to_bf16(const float* __restrict__ x,
                                 const float* __restrict__ W,
                                 unsigned short* __restrict__ xb,
                                 unsigned short* __restrict__ wb,
                                 int blocks_each) {
    int b = blockIdx.x;
    const float* src = x;
    unsigned short* dst = xb;
    if (b >= blocks_each) { b -= blocks_each; src = W; dst = wb; }
    const int i = (b * 256 + threadIdx.x) * 8;
    float4 f0 = *(const float4*)(src + i);
    float4 f1 = *(const float4*)(src + i + 4);
    u16x8 o;
    o[0] = f2bf(f0.x); o[1] = f2bf(f0.y); o[2] = f2bf(f0.z); o[3] = f2bf(f0.w);
    o[4] = f2bf(f1.x); o[5] = f2bf(f1.y); o[6] = f2bf(f1.z); o[7] = f2bf(f1.w);
    *(u16x8*)(dst + i) = o;
}

// ---------- async global->LDS, 16B per lane (dest = wave-uniform base + lane*16) ----------
__device__ __forceinline__ void gl_lds16(const void* g, void* l) {
    __builtin_amdgcn_global_load_lds(
        (const __attribute__((address_space(1))) void*)g,
        (__attribute__((address_space(3))) void*)l,
        16, 0, 0);
}

// ============================================================================
// V5 = V4 with the B-read base bug fixed (brow0 had +16384 double-counted
// with R=B0/B1 -> B frags read buf1's A region / out-of-bounds), and 2
// rotating fragment sets (pA/pB) instead of 4 to keep VGPR < 256.
//
// 256x256 tile, BK=64, 8-wave, 32x32x16 MFMA, big-block schedule:
//  * Per wave: 4m x 2n 32x32 tiles (128x64 output), acc = 8 x f32x16.
//  * ONE read/MFMA stream per K-tile, 2 barriers/K-tile: 24 ds_read_b128
//    interleaved with 4 MFMA clusters (read slice s+2 while computing s/s+1)
//    in a single basic block -> counted lgkmcnt, MFMA shadows the LDS drain.
//  * Tile end: lgkmcnt(0); BAR; stage all 4 half-tiles of t+2 into the SAME
//    buffer; vmcnt(8) = t+1 retired, t+2's 8 loads in flight (never 0 in
//    main loop); BAR (t+1 globally visible: each wave counted its own 8,
//    barrier makes it collective).
//  * LDS: [buf:+32768][A0:+0][A1:+8192][B0:+16384][B1:+24576] shorts; region
//    = 256 rows x 32 shorts (one 32-wide k-window), granule slot q holds
//    global granule q ^ ((row>>1)&3)  (bank-conflict-free; measured 0).
// ============================================================================
__global__ __launch_bounds__(512, 2) void gemm256(
    const unsigned short* __restrict__ A,   // [M,K] bf16
    const unsigned short* __restrict__ B,   // [N,K] bf16
    const float* __restrict__ bias, float* __restrict__ C) {

    __shared__ __align__(16) unsigned short sh[65536];   // 128 KiB

    const int tid  = threadIdx.x;
    const int wave = tid >> 6;
    const int lane = tid & 63;
    const int r32  = lane & 31;
    const int hi   = lane >> 5;        // 0 or 1
    const int wm   = wave >> 2;        // 0..1  (M half: 128 rows)
    const int wn   = wave & 3;         // 0..3  (N quarter: 64 cols)

    // XCD swizzle: 256 blocks over 8 XCDs; per-XCD 4x8 patch of 256^2 tiles.
    const int bid = blockIdx.x;
    const int xcd = bid & 7;
    const int idx = bid >> 3;                          // 0..31
    const int mt  = ((xcd >> 1) << 2) + (idx >> 3);    // 0..15
    const int nt  = ((xcd & 1) << 3) + (idx & 7);      // 0..15
    const size_t bm = (size_t)mt << 8;
    const size_t bn = (size_t)nt << 8;

    // ---- staging geometry: 512 thr x 16B = 8KB -> 2 loads per 16KB region
    const int srow  = tid >> 2;                              // 0..127
    const int sg8   = ((tid & 3) ^ ((tid >> 3) & 3)) << 3;   // inverse-swizzled src granule
    const int wslot = wave << 9;                             // wave*512 shorts

    const unsigned short* Abase = A + bm * K_DIM;
    const unsigned short* Bbase = B + bn * K_DIM;

    auto stage = [&](const unsigned short* __restrict__ P, int dstbase, int kelem) {
        const unsigned short* s0 = P + (size_t)srow * K_DIM + kelem + sg8;
        gl_lds16(s0,                        &sh[dstbase + wslot]);
        gl_lds16(s0 + (size_t)128 * K_DIM,  &sh[dstbase + 4096 + wslot]);
    };

    // ---- read-side (32x32x16): k-step s reads granule 2*(s&1)+hi of region
    // (s>>1); slot = granule ^ ((row>>1)&3), and (row>>1)&3 == (r32>>1)&3.
    const int sw    = (r32 >> 1) & 3;
    const int koff0 = (hi ^ sw) << 3;        // k-window 0 (shorts)
    const int koff1 = koff0 ^ 16;            // k-window 1 (slot ^ 2)
    const int arow0 = (wm * 128 + r32) * 32;   // + m*1024 per m-tile (region-rel)
    const int brow0 = (wn * 64  + r32) * 32;   // + n*1024 per n-tile (region-rel)

    f32x16 acc[4][2] = {};   // 4 m-tiles x 2 n-tiles of 32x32 (128 regs)

#define RDA(dst, R, W)                                                        \
    _Pragma("unroll")                                                         \
    for (int m = 0; m < 4; m++)                                               \
        dst[m] = *(const bf16x8*)&sh[(R) + arow0 + m * 1024 + (W)];
#define RDB(dst, R, W)                                                        \
    _Pragma("unroll")                                                         \
    for (int n = 0; n < 2; n++)                                               \
        dst[n] = *(const bf16x8*)&sh[(R) + brow0 + n * 1024 + (W)];

#define MM(AF, BF)                                                            \
    __builtin_amdgcn_s_setprio(1);                                            \
    _Pragma("unroll")                                                         \
    for (int m = 0; m < 4; m++)                                               \
        _Pragma("unroll")                                                     \
        for (int n = 0; n < 2; n++)                                           \
            acc[m][n] = __builtin_amdgcn_mfma_f32_32x32x16_bf16(              \
                AF[m], BF[n], acc[m][n], 0, 0, 0);                            \
    __builtin_amdgcn_s_setprio(0);

    // ---- prologue: stage tile0 -> buf0, tile1 -> buf1; vmcnt(8) = t0 landed
    stage(Abase, 0,             0);
    stage(Abase, 8192,          32);
    stage(Bbase, 16384,         0);
    stage(Bbase, 24576,         32);
    stage(Abase, 32768 + 0,     64);
    stage(Abase, 32768 + 8192,  96);
    stage(Bbase, 32768 + 16384, 64);
    stage(Bbase, 32768 + 24576, 96);
    asm volatile("s_waitcnt vmcnt(8)" ::: "memory");
    __builtin_amdgcn_s_barrier();

    // stmode: 0 = steady (stage t+2, vmcnt(8)), 1 = t62 (no stage, vmcnt(0)),
    //         2 = t63 (compute only).  buf literal at call sites.
    auto ktile = [&](const int buf, const int t, const int stmode) {
        const int A0 = buf, A1 = buf + 8192;
        const int B0 = buf + 16384, B1 = buf + 24576;
        bf16x8 pAa[4], pBa[4];
        bf16x8 pAb[2], pBb[2];

        // k-slice pipeline (2 rotating frag sets; WAR enforced by reg deps):
        RDA(pAa, A0, koff0) RDB(pAb, B0, koff0)      // s0 -> set A
        RDA(pBa, A0, koff1) RDB(pBb, B0, koff1)      // s1 -> set B
        MM(pAa, pAb)                                 // s0
        RDA(pAa, A1, koff0) RDB(pAb, B1, koff0)      // s2 -> set A (after s0 MM)
        MM(pBa, pBb)                                 // s1
        RDA(pBa, A1, koff1) RDB(pBb, B1, koff1)      // s3 -> set B (after s1 MM)
        MM(pAa, pAb)                                 // s2
        MM(pBa, pBb)                                 // s3

        if (stmode == 2) return;                     // straight to epilogue

        asm volatile("s_waitcnt lgkmcnt(0)" ::: "memory");  // buf reads done
        __builtin_amdgcn_s_barrier();                // ... in EVERY wave

        if (stmode == 0) {                           // overwrite buf with t+2
            const int k2 = (t + 2) * 64;
            stage(Abase, A0, k2);
            stage(Abase, A1, k2 + 32);
            stage(Bbase, B0, k2);
            stage(Bbase, B1, k2 + 32);
            asm volatile("s_waitcnt vmcnt(8)" ::: "memory");  // t+1 landed
        } else {
            asm volatile("s_waitcnt vmcnt(0)" ::: "memory");  // drain t63
        }
        __builtin_amdgcn_s_barrier();                // t+1 globally visible
    };

    for (int t = 0; t < 62; t += 2) {
        ktile(0,     t,     0);
        ktile(32768, t + 1, 0);
    }
    ktile(0,     62, 1);
    ktile(32768, 63, 2);
#undef RDA
#undef RDB
#undef MM

    // ---- epilogue: 32x32 C/D layout: col = lane&31, row = (reg&3)+8*(reg>>2)+4*hi
#pragma unroll
    for (int m = 0; m < 4; m++) {
        const size_t rowb = bm + wm * 128 + m * 32 + 4 * hi;
#pragma unroll
        for (int n = 0; n < 2; n++) {
            const size_t col = bn + wn * 64 + n * 32 + r32;
            const float bv = bias[col];
#pragma unroll
            for (int reg = 0; reg < 16; reg++) {
                const size_t row = rowb + (reg & 3) + 8 * (reg >> 2);
                C[row * N_DIM + col] = acc[m][n][reg] + bv;
            }
        }
    }
}

// ============================================================================
// Fallback (no workspace): previous-session 128x128 fp32-input kernel, verbatim.
// ============================================================================
#define BM 128
#define BN 128
#define BK 32

__global__ __launch_bounds__(256) void gemm_bt_f32(
    const float* __restrict__ Aptr, const float* __restrict__ Bptr,
    const float* __restrict__ bias, float* __restrict__ C) {

    __shared__ __align__(16) unsigned short As[BM * BK];
    __shared__ __align__(16) unsigned short Bs[BN * BK];

    const int tid  = threadIdx.x;
    const int wave = tid >> 6;
    const int lane = tid & 63;
    const int r32  = lane & 31;
    const int hi   = lane >> 5;

    const int bid = blockIdx.x;
    const int xcd = bid & 7;
    const int idx = bid >> 3;
    const int mt  = ((xcd & 1) << 4) + (idx & 15);
    const int nt  = (((xcd >> 1) & 3) << 3) + (idx >> 4);
    const int bm  = mt * BM;
    const int bn  = nt * BN;

    const int wm = (wave & 1) * 64;
    const int wn = (wave >> 1) * 64;

    f32x16 acc[2][2] = {};
    const int sw = (r32 >> 1) & 3;

    for (int k0 = 0; k0 < K_DIM; k0 += BK) {
        __syncthreads();
        {
            const int r  = tid >> 1;
            const int q0 = (tid & 1) << 1;
            const int s  = (r >> 1) & 3;
            {
                const float* sp = &Aptr[(size_t)(bm + r) * K_DIM + k0 + (q0 << 3)];
                float4 f0 = *(const float4*)(sp + 0);
                float4 f1 = *(const float4*)(sp + 4);
                float4 f2 = *(const float4*)(sp + 8);
                float4 f3 = *(const float4*)(sp + 12);
                u16x8 o0, o1;
                o0[0]=f2bf(f0.x); o0[1]=f2bf(f0.y); o0[2]=f2bf(f0.z); o0[3]=f2bf(f0.w);
                o0[4]=f2bf(f1.x); o0[5]=f2bf(f1.y); o0[6]=f2bf(f1.z); o0[7]=f2bf(f1.w);
                o1[0]=f2bf(f2.x); o1[1]=f2bf(f2.y); o1[2]=f2bf(f2.z); o1[3]=f2bf(f2.w);
                o1[4]=f2bf(f3.x); o1[5]=f2bf(f3.y); o1[6]=f2bf(f3.z); o1[7]=f2bf(f3.w);
                *(u16x8*)&As[r * BK + ((q0 ^ s) << 3)]       = o0;
                *(u16x8*)&As[r * BK + (((q0 + 1) ^ s) << 3)] = o1;
            }
            {
                const float* sp = &Bptr[(size_t)(bn + r) * K_DIM + k0 + (q0 << 3)];
                float4 f0 = *(const float4*)(sp + 0);
                float4 f1 = *(const float4*)(sp + 4);
                float4 f2 = *(const float4*)(sp + 8);
                float4 f3 = *(const float4*)(sp + 12);
                u16x8 o0, o1;
                o0[0]=f2bf(f0.x); o0[1]=f2bf(f0.y); o0[2]=f2bf(f0.z); o0[3]=f2bf(f0.w);
                o0[4]=f2bf(f1.x); o0[5]=f2bf(f1.y); o0[6]=f2bf(f1.z); o0[7]=f2bf(f1.w);
                o1[0]=f2bf(f2.x); o1[1]=f2bf(f2.y); o1[2]=f2bf(f2.z); o1[3]=f2bf(f2.w);
                o1[4]=f2bf(f3.x); o1[5]=f2bf(f3.y); o1[6]=f2bf(f3.z); o1[7]=f2bf(f3.w);
                *(u16x8*)&Bs[r * BK + ((q0 ^ s) << 3)]       = o0;
                *(u16x8*)&Bs[r * BK + (((q0 + 1) ^ s) << 3)] = o1;
            }
        }
        __syncthreads();

        bf16x8 af[2][2], bfv[2][2];
#pragma unroll
        for (int t = 0; t < 2; t++)
#pragma unroll
            for (int h = 0; h < 2; h++) {
                const int koffl = (((hi + 2 * h) ^ sw)) << 3;
                af[t][h]  = *(const bf16x8*)&As[(wm + t * 32 + r32) * BK + koffl];
                bfv[t][h] = *(const bf16x8*)&Bs[(wn + t * 32 + r32) * BK + koffl];
            }
#pragma unroll
        for (int h = 0; h < 2; h++)
#pragma unroll
            for (int i = 0; i < 2; i++)
#pragma unroll
                for (int j = 0; j < 2; j++)
                    acc[i][j] = __builtin_amdgcn_mfma_f32_32x32x16_bf16(
                        af[i][h], bfv[j][h], acc[i][j], 0, 0, 0);
    }

#pragma unroll
    for (int i = 0; i < 2; i++) {
        const int rowb = bm + wm + i * 32 + 4 * hi;
#pragma unroll
        for (int j = 0; j < 2; j++) {
            const int col = bn + wn + j * 32 + r32;
            const float bv = bias[col];
#pragma unroll
            for (int reg = 0; reg < 16; reg++) {
                const int row = rowb + (reg & 3) + 8 * (reg >> 2);
                C[(size_t)row * N_DIM + col] = acc[i][j][reg] + bv;
            }
        }
    }
}

extern "C" void kernel_launch(void* const* d_in, const int* in_sizes, int n_in,
                              void* d_out, int out_size, void* d_ws, size_t ws_size,
                              hipStream_t stream) {
    const float* x = (const float*)d_in[0];   // [M, K]
    const float* W = (const float*)d_in[1];   // [N, K]
    const float* b = (const float*)d_in[2];   // [N]
    float* out = (float*)d_out;               // [M, N]

    const size_t elems = (size_t)M_DIM * K_DIM;
    const size_t need  = 2 * elems * sizeof(unsigned short);  // 64 MB

    if (ws_size >= need) {
        unsigned short* xb = (unsigned short*)d_ws;
        unsigned short* wb = xb + elems;
        const int blocks_each = (int)(elems / (256 * 8));     // 8192
        cvt2_f32_to_bf16<<<2 * blocks_each, 256, 0, stream>>>(x, W, xb, wb, blocks_each);
        dim3 grid((M_DIM / 256) * (N_DIM / 256));             // 256 blocks = 1/CU
        gemm256<<<grid, dim3(512), 0, stream>>>(xb, wb, b, out);
    } else {
        dim3 grid((M_DIM / BM) * (N_DIM / BN));
        gemm_bt_f32<<<grid, dim3(256), 0, stream>>>(x, W, b, out);
    }
}

// Round 6
// 289.711 us; speedup vs baseline: 1.0152x; 1.0152x over previous
//
#include <hip/hip_runtime.h>
#include <hip/hip_bf16.h>

#define K_DIM 4096
#define N_DIM 4096
#define M_DIM 4096

typedef __attribute__((ext_vector_type(8)))  short bf16x8;    // 8 bf16, 4 VGPRs
typedef __attribute__((ext_vector_type(4)))  float f32x4;     // 16x16 MFMA acc
typedef __attribute__((ext_vector_type(16))) float f32x16;    // 32x32 MFMA acc (fallback)
typedef __attribute__((ext_vector_type(8)))  unsigned short u16x8;

// ---------- fp32 -> bf16 (round-to-nearest-even) ----------
__device__ __forceinline__ unsigned short f2bf(float f) {
    union { float f; unsigned int u; } v; v.f = f;
    unsigned int u = v.u;
    return (unsigned short)((u + 0x7fffu + ((u >> 16) & 1u)) >> 16);
}

// ---------- fused convert: x and W in one launch ----------
__global__ void cvt2_f32_to_bf16(const float* __restrict__ x,
                                 const float* __restrict__ W,
                                 unsigned short* __restrict__ xb,
                                 unsigned short* __restrict__ wb,
                                 int blocks_each) {
    int b = blockIdx.x;
    const float* src = x;
    unsigned short* dst = xb;
    if (b >= blocks_each) { b -= blocks_each; src = W; dst = wb; }
    const int i = (b * 256 + threadIdx.x) * 8;
    float4 f0 = *(const float4*)(src + i);
    float4 f1 = *(const float4*)(src + i + 4);
    u16x8 o;
    o[0] = f2bf(f0.x); o[1] = f2bf(f0.y); o[2] = f2bf(f0.z); o[3] = f2bf(f0.w);
    o[4] = f2bf(f1.x); o[5] = f2bf(f1.y); o[6] = f2bf(f1.z); o[7] = f2bf(f1.w);
    *(u16x8*)(dst + i) = o;
}

// ---------- async global->LDS, 16B per lane (dest = wave-uniform base + lane*16) ----------
__device__ __forceinline__ void gl_lds16(const void* g, void* l) {
    __builtin_amdgcn_global_load_lds(
        (const __attribute__((address_space(1))) void*)g,
        (__attribute__((address_space(3))) void*)l,
        16, 0, 0);
}

// ============================================================================
// V6 = V1's verified 4-phase 16x16x32 kernel (0 bank conflicts, correct) +
// the m201 template's waitcnt discipline:
//   per phase: {ds_reads issued; stage; sched_barrier(0); s_barrier;
//               asm lgkmcnt(0); sched_barrier(0); setprio1; 16 MFMA;
//               setprio0; s_barrier}
// Reads stay IN FLIGHT across the first barrier; each wave's lgkm(0) waits
// only its OWN reads -> waves un-stall staggered as the LDS pipe drains ->
// early waves' MFMAs overlap late waves' reads (the pipes co-run instead of
// alternating).  sched_barrier(0) after lgkm0 is mandatory (rule 18: hipcc
// hoists register-only MFMAs past inline-asm waitcnt).
// Safety: each wave's lgkm0 precedes its phase-end barrier => all reads of
// phase p complete before ANY wave enters p+1; every region overwrite is
// >=1 full barrier after its last consumption.  vmcnt(6) once per K-tile
// (3 half-tiles = 6 loads in flight, in-order retirement), + barrier =
// tile t+1 globally visible before its first read.
// ============================================================================
__global__ __launch_bounds__(512, 2) void gemm256(
    const unsigned short* __restrict__ A,   // [M,K] bf16
    const unsigned short* __restrict__ B,   // [N,K] bf16
    const float* __restrict__ bias, float* __restrict__ C) {

    __shared__ __align__(16) unsigned short sh[65536];   // 128 KiB

    const int tid  = threadIdx.x;
    const int wave = tid >> 6;
    const int lane = tid & 63;
    const int l16  = lane & 15;
    const int gq   = lane >> 4;        // k-granule 0..3
    const int wm   = wave >> 2;        // 0..1  (M row of wave grid)
    const int wn   = wave & 3;         // 0..3  (N col of wave grid)

    // XCD swizzle: 256 blocks over 8 XCDs; per-XCD 4x8 patch of 256^2 tiles.
    const int bid = blockIdx.x;
    const int xcd = bid & 7;
    const int idx = bid >> 3;                          // 0..31
    const int mt  = ((xcd >> 1) << 2) + (idx >> 3);    // 0..15
    const int nt  = ((xcd & 1) << 3) + (idx & 7);      // 0..15
    const size_t bm = (size_t)mt << 8;
    const size_t bn = (size_t)nt << 8;

    // ---- staging geometry: 512 thr x 16B = 8KB -> 2 loads per 16KB half-tile
    const int srow  = tid >> 2;                              // 0..127
    const int sg8   = ((tid & 3) ^ ((tid >> 3) & 3)) << 3;   // inverse-swizzled src granule
    const int wslot = wave << 9;                             // wave*512 shorts

    const unsigned short* Abase = A + bm * K_DIM;
    const unsigned short* Bbase = B + bn * K_DIM;

    auto stage = [&](const unsigned short* __restrict__ P, int dstbase, int kelem) {
        const unsigned short* s0 = P + (size_t)srow * K_DIM + kelem + sg8;
        gl_lds16(s0,                        &sh[dstbase + wslot]);
        gl_lds16(s0 + (size_t)128 * K_DIM,  &sh[dstbase + 4096 + wslot]);
    };

    // ---- read-side: frag row = base + l16; swizzle term is frag-invariant.
    // 8 consecutive lanes cover all 8 bank-quads -> conflict-free (measured 0).
    const int koff = (gq ^ ((l16 >> 1) & 3)) << 3;           // shorts
    const int aoff = ((wm << 7) + l16) * 32 + koff;
    const int boff = ((wn << 6) + l16) * 32 + koff;

    f32x4 acc[8][4] = {};   // 8 m-frags x 4 n-frags (128 acc regs)

    bf16x8 a[4], b[4];

#define RD_A(base, fbase)                                                     \
    _Pragma("unroll")                                                         \
    for (int f = 0; f < 4; f++)                                               \
        a[f] = *(const bf16x8*)&sh[(base) + aoff + ((fbase) + f) * 512];
#define RD_B(base)                                                            \
    _Pragma("unroll")                                                         \
    for (int n = 0; n < 4; n++)                                               \
        b[n] = *(const bf16x8*)&sh[(base) + boff + n * 512];

// barrier, then wait own reads, then pin MFMAs behind the wait (rule 18)
#define PHASE_SYNC                                                            \
    __builtin_amdgcn_sched_barrier(0);                                        \
    __builtin_amdgcn_s_barrier();                                             \
    asm volatile("s_waitcnt lgkmcnt(0)" ::: "memory");                        \
    __builtin_amdgcn_sched_barrier(0);

#define PHASE_MFMA(FOFF)                                                      \
    __builtin_amdgcn_s_setprio(1);                                            \
    _Pragma("unroll")                                                         \
    for (int f = 0; f < 4; f++)                                               \
        _Pragma("unroll")                                                     \
        for (int n = 0; n < 4; n++)                                           \
            acc[f + FOFF][n] = __builtin_amdgcn_mfma_f32_16x16x32_bf16(       \
                a[f], b[n], acc[f + FOFF][n], 0, 0, 0);                       \
    __builtin_amdgcn_s_setprio(0);

    // ---- prologue: tile0 (4 half-tiles) + tile1 first 3; vmcnt(6) = 14-8,
    // in-order retirement => tile0's 8 loads landed.
    stage(Abase, 0,             0);     // A k0 (t0)
    stage(Bbase, 16384,         0);     // B k0 (t0)
    stage(Abase, 8192,          32);    // A k1 (t0)
    stage(Bbase, 24576,         32);    // B k1 (t0)
    stage(Bbase, 32768 + 16384, 64);    // B k0 (t1)
    stage(Abase, 32768 + 0,     64);    // A k0 (t1)
    stage(Bbase, 32768 + 24576, 96);    // B k1 (t1)
    asm volatile("s_waitcnt vmcnt(6)" ::: "memory");   // tile0 landed
    __builtin_amdgcn_s_barrier();

    // stmode: 0 = steady, 1 = t62 (stage A1(63) only, drain), 2 = t63
    auto ktile = [&](const int buf, const int t, const int stmode) {
        const int obuf = buf ^ 32768;
        const int A0 = buf, A1 = buf + 8192, B0 = buf + 16384, B1 = buf + 24576;

        // ---- ph1: (m-half 0, k-half 0); stage A-k1(t+1) -> other buffer
        RD_A(A0, 0)
        RD_B(B0)
        if (stmode <= 1) stage(Abase, obuf + 8192, (t + 1) * 64 + 32);
        PHASE_SYNC
        PHASE_MFMA(0)
        __builtin_amdgcn_s_barrier();

        // ---- ph2: (m-half 1, k-half 0); b[] reused; stage B-k0(t+2)
        //      (B0(t) reads completed before ph1's end barrier in every wave)
        RD_A(A0, 4)
        if (stmode == 0) stage(Bbase, B0, (t + 2) * 64);
        PHASE_SYNC
        PHASE_MFMA(4)
        __builtin_amdgcn_s_barrier();

        // ---- ph3: (m-half 0, k-half 1); stage A-k0(t+2)
        RD_A(A1, 0)
        RD_B(B1)
        if (stmode == 0) stage(Abase, A0, (t + 2) * 64);
        PHASE_SYNC
        PHASE_MFMA(0)
        __builtin_amdgcn_s_barrier();

        // ---- ph4: (m-half 1, k-half 1); stage B-k1(t+2); counted vmcnt
        RD_A(A1, 4)
        if (stmode == 0) {
            stage(Bbase, B1, (t + 2) * 64 + 32);
            asm volatile("s_waitcnt vmcnt(6)" ::: "memory");  // tile t+1 landed
        } else if (stmode == 1) {
            asm volatile("s_waitcnt vmcnt(0)" ::: "memory");  // drain tail
        }
        PHASE_SYNC
        PHASE_MFMA(4)
        if (stmode != 2) __builtin_amdgcn_s_barrier();        // t+1 visible
    };

    for (int t = 0; t < 62; t += 2) {
        ktile(0,     t,     0);
        ktile(32768, t + 1, 0);
    }
    ktile(0,     62, 1);
    ktile(32768, 63, 2);
#undef PHASE_MFMA
#undef PHASE_SYNC
#undef RD_A
#undef RD_B

    // ---- epilogue: 16x16 C/D layout: col = lane&15, row = (lane>>4)*4 + reg
    const size_t row0 = bm + (wm << 7) + (gq << 2);
    const size_t col0 = bn + (wn << 6) + l16;
#pragma unroll
    for (int n = 0; n < 4; n++) {
        const size_t col = col0 + n * 16;
        const float bv = bias[col];
#pragma unroll
        for (int f = 0; f < 8; f++) {
            const size_t r = row0 + f * 16;
#pragma unroll
            for (int j = 0; j < 4; j++)
                C[(r + j) * N_DIM + col] = acc[f][n][j] + bv;
        }
    }
}

// ============================================================================
// Fallback (no workspace): previous-session 128x128 fp32-input kernel, verbatim.
// ============================================================================
#define BM 128
#define BN 128
#define BK 32

__global__ __launch_bounds__(256) void gemm_bt_f32(
    const float* __restrict__ Aptr, const float* __restrict__ Bptr,
    const float* __restrict__ bias, float* __restrict__ C) {

    __shared__ __align__(16) unsigned short As[BM * BK];
    __shared__ __align__(16) unsigned short Bs[BN * BK];

    const int tid  = threadIdx.x;
    const int wave = tid >> 6;
    const int lane = tid & 63;
    const int r32  = lane & 31;
    const int hi   = lane >> 5;

    const int bid = blockIdx.x;
    const int xcd = bid & 7;
    const int idx = bid >> 3;
    const int mt  = ((xcd & 1) << 4) + (idx & 15);
    const int nt  = (((xcd >> 1) & 3) << 3) + (idx >> 4);
    const int bm  = mt * BM;
    const int bn  = nt * BN;

    const int wm = (wave & 1) * 64;
    const int wn = (wave >> 1) * 64;

    f32x16 acc[2][2] = {};
    const int sw = (r32 >> 1) & 3;

    for (int k0 = 0; k0 < K_DIM; k0 += BK) {
        __syncthreads();
        {
            const int r  = tid >> 1;
            const int q0 = (tid & 1) << 1;
            const int s  = (r >> 1) & 3;
            {
                const float* sp = &Aptr[(size_t)(bm + r) * K_DIM + k0 + (q0 << 3)];
                float4 f0 = *(const float4*)(sp + 0);
                float4 f1 = *(const float4*)(sp + 4);
                float4 f2 = *(const float4*)(sp + 8);
                float4 f3 = *(const float4*)(sp + 12);
                u16x8 o0, o1;
                o0[0]=f2bf(f0.x); o0[1]=f2bf(f0.y); o0[2]=f2bf(f0.z); o0[3]=f2bf(f0.w);
                o0[4]=f2bf(f1.x); o0[5]=f2bf(f1.y); o0[6]=f2bf(f1.z); o0[7]=f2bf(f1.w);
                o1[0]=f2bf(f2.x); o1[1]=f2bf(f2.y); o1[2]=f2bf(f2.z); o1[3]=f2bf(f2.w);
                o1[4]=f2bf(f3.x); o1[5]=f2bf(f3.y); o1[6]=f2bf(f3.z); o1[7]=f2bf(f3.w);
                *(u16x8*)&As[r * BK + ((q0 ^ s) << 3)]       = o0;
                *(u16x8*)&As[r * BK + (((q0 + 1) ^ s) << 3)] = o1;
            }
            {
                const float* sp = &Bptr[(size_t)(bn + r) * K_DIM + k0 + (q0 << 3)];
                float4 f0 = *(const float4*)(sp + 0);
                float4 f1 = *(const float4*)(sp + 4);
                float4 f2 = *(const float4*)(sp + 8);
                float4 f3 = *(const float4*)(sp + 12);
                u16x8 o0, o1;
                o0[0]=f2bf(f0.x); o0[1]=f2bf(f0.y); o0[2]=f2bf(f0.z); o0[3]=f2bf(f0.w);
                o0[4]=f2bf(f1.x); o0[5]=f2bf(f1.y); o0[6]=f2bf(f1.z); o0[7]=f2bf(f1.w);
                o1[0]=f2bf(f2.x); o1[1]=f2bf(f2.y); o1[2]=f2bf(f2.z); o1[3]=f2bf(f2.w);
                o1[4]=f2bf(f3.x); o1[5]=f2bf(f3.y); o1[6]=f2bf(f3.z); o1[7]=f2bf(f3.w);
                *(u16x8*)&Bs[r * BK + ((q0 ^ s) << 3)]       = o0;
                *(u16x8*)&Bs[r * BK + (((q0 + 1) ^ s) << 3)] = o1;
            }
        }
        __syncthreads();

        bf16x8 af[2][2], bfv[2][2];
#pragma unroll
        for (int t = 0; t < 2; t++)
#pragma unroll
            for (int h = 0; h < 2; h++) {
                const int koffl = (((hi + 2 * h) ^ sw)) << 3;
                af[t][h]  = *(const bf16x8*)&As[(wm + t * 32 + r32) * BK + koffl];
                bfv[t][h] = *(const bf16x8*)&Bs[(wn + t * 32 + r32) * BK + koffl];
            }
#pragma unroll
        for (int h = 0; h < 2; h++)
#pragma unroll
            for (int i = 0; i < 2; i++)
#pragma unroll
                for (int j = 0; j < 2; j++)
                    acc[i][j] = __builtin_amdgcn_mfma_f32_32x32x16_bf16(
                        af[i][h], bfv[j][h], acc[i][j], 0, 0, 0);
    }

#pragma unroll
    for (int i = 0; i < 2; i++) {
        const int rowb = bm + wm + i * 32 + 4 * hi;
#pragma unroll
        for (int j = 0; j < 2; j++) {
            const int col = bn + wn + j * 32 + r32;
            const float bv = bias[col];
#pragma unroll
            for (int reg = 0; reg < 16; reg++) {
                const int row = rowb + (reg & 3) + 8 * (reg >> 2);
                C[(size_t)row * N_DIM + col] = acc[i][j][reg] + bv;
            }
        }
    }
}

extern "C" void kernel_launch(void* const* d_in, const int* in_sizes, int n_in,
                              void* d_out, int out_size, void* d_ws, size_t ws_size,
                              hipStream_t stream) {
    const float* x = (const float*)d_in[0];   // [M, K]
    const float* W = (const float*)d_in[1];   // [N, K]
    const float* b = (const float*)d_in[2];   // [N]
    float* out = (float*)d_out;               // [M, N]

    const size_t elems = (size_t)M_DIM * K_DIM;
    const size_t need  = 2 * elems * sizeof(unsigned short);  // 64 MB

    if (ws_size >= need) {
        unsigned short* xb = (unsigned short*)d_ws;
        unsigned short* wb = xb + elems;
        const int blocks_each = (int)(elems / (256 * 8));     // 8192
        cvt2_f32_to_bf16<<<2 * blocks_each, 256, 0, stream>>>(x, W, xb, wb, blocks_each);
        dim3 grid((M_DIM / 256) * (N_DIM / 256));             // 256 blocks = 1/CU
        gemm256<<<grid, dim3(512), 0, stream>>>(xb, wb, b, out);
    } else {
        dim3 grid((M_DIM / BM) * (N_DIM / BN));
        gemm_bt_f32<<<grid, dim3(256), 0, stream>>>(x, W, b, out);
    }
}